// Round 4
// baseline (166.142 us; speedup 1.0000x reference)
//
#include <hip/hip_runtime.h>
#include <hip/hip_bf16.h>

// B=2, H=16, S=2048, D=64, DMODEL=1024
// Round 14: r13 post-mortem -- no pipe >40% (LDS 37, VALU 39, MFMA 7);
// latency-bound. Root cause found by arithmetic: total waves = 4096 in every
// prior geometry (q-groups x 2 kh) = 16 waves/CU hard cap. Fix: kh 4-way
// split -> 8192 waves; single-buffered K/V (two lgkm-barriers/iter, PV
// overlaps staging) -> 36,864 B LDS -> 4 blocks/CU x 8 waves = 32 waves/CU,
// 2x TLP. XCD-chunked swizzle (1024=8x128): each XCD's resident blocks = 4
// (h,bz) pairs -> K/V 2MB fits 4MB L2 -> FETCH should drop 74->~40MB.
// convert_all / proj untouched (isolate attribution).

typedef float  f32x16 __attribute__((ext_vector_type(16)));
typedef float  f32x4v __attribute__((ext_vector_type(4)));
typedef float  f32x2v __attribute__((ext_vector_type(2)));
typedef __bf16 bf16x8 __attribute__((ext_vector_type(8)));
typedef __bf16 bf16x4 __attribute__((ext_vector_type(4)));
typedef __bf16 bf16x2 __attribute__((ext_vector_type(2)));

static constexpr int Bn = 2, Hn = 16, Sn = 2048, Dn = 64, DM = 1024;
static constexpr size_t QKV_ELEMS = (size_t)Bn * Hn * Sn * Dn;   // 4,194,304

#define QSCALE 0.18033688011112042f   // 0.125 * log2(e)

// lgkm-only barrier: own LDS ops drained, global prefetch stays in flight.
#define LGKM_BARRIER() do {                                  \
    asm volatile("s_waitcnt lgkmcnt(0)" ::: "memory");       \
    __builtin_amdgcn_s_barrier();                            \
  } while (0)

#if __has_builtin(__builtin_amdgcn_cvt_pk_bf16_f32)
static __device__ __forceinline__ unsigned pack2(float a, float b) {
  bf16x2 t = __builtin_amdgcn_cvt_pk_bf16_f32(a, b);
  union { bf16x2 v; unsigned u; } c; c.v = t; return c.u;
}
#else
static __device__ __forceinline__ unsigned pack2(float a, float b) {
  union { __bf16 h; unsigned short s; } ua, ub;
  ua.h = (__bf16)a; ub.h = (__bf16)b;
  return (unsigned)ua.s | ((unsigned)ub.s << 16);
}
#endif

static __device__ __forceinline__ void unzip8(const unsigned* wds, bf16x8* r0, bf16x8* r1) {
  union { unsigned u[4]; bf16x8 v; } a, b;
#pragma unroll
  for (int i = 0; i < 4; ++i) {
    unsigned lo = wds[2 * i], hi = wds[2 * i + 1];
    a.u[i] = (lo & 0xffffu) | (hi << 16);
    b.u[i] = (lo >> 16) | (hi & 0xffff0000u);
  }
  *r0 = a.v; *r1 = b.v;
}

// ------------------------------------------------- fused converts (1 kernel)
// [0,2048) K cvt; [2048,3072) V-T; [3072,3328) W-T. (Q handled inside attn.)
__global__ __launch_bounds__(256) void convert_all(
    const float* __restrict__ k,
    const float* __restrict__ v, const float* __restrict__ w,
    __bf16* __restrict__ ko,
    __bf16* __restrict__ vt, __bf16* __restrict__ wt) {
  __shared__ __bf16 T[64][74];
  const int bid = blockIdx.x, t = threadIdx.x;

  if (bid < 2048) {
    size_t i = ((size_t)bid * 256 + t) * 8;
    f32x4v a = *(const f32x4v*)(k + i);
    f32x4v b = *(const f32x4v*)(k + i + 4);
    bf16x8 o;
#pragma unroll
    for (int j = 0; j < 4; ++j) { o[j] = (__bf16)a[j]; o[4 + j] = (__bf16)b[j]; }
    *(bf16x8*)(ko + i) = o;
    return;
  }

  const float* s0;
  __bf16* dst0;
  size_t dst_stride;
  {
    const int r = t >> 2, c0 = (t & 3) * 16;
    if (bid < 3072) {
      const int idx = bid - 2048;
      const int kv0 = (idx & 31) * 64, bh = idx >> 5;
      s0 = v + ((size_t)bh * Sn + kv0 + r) * Dn + c0;
      dst0 = vt + (size_t)bh * Dn * Sn + kv0;
      dst_stride = Sn;
    } else {
      const int idx = bid - 3072;
      const int nt = (idx & 15) * 64, kt = (idx >> 4) * 64;
      s0 = w + (size_t)(kt + r) * DM + nt + c0;
      dst0 = wt + (size_t)nt * DM + kt;
      dst_stride = DM;
    }
    union { bf16x8 v8; unsigned u[4]; } o0, o1;
#pragma unroll
    for (int i = 0; i < 2; ++i) {
      f32x4v f = *(const f32x4v*)(s0 + i * 4);
#pragma unroll
      for (int j = 0; j < 4; ++j) o0.v8[i * 4 + j] = (__bf16)f[j];
    }
#pragma unroll
    for (int i = 0; i < 2; ++i) {
      f32x4v f = *(const f32x4v*)(s0 + 8 + i * 4);
#pragma unroll
      for (int j = 0; j < 4; ++j) o1.v8[i * 4 + j] = (__bf16)f[j];
    }
#pragma unroll
    for (int j = 0; j < 4; ++j) {
      *(unsigned*)&T[r][c0 + 2 * j]     = o0.u[j];
      *(unsigned*)&T[r][c0 + 8 + 2 * j] = o1.u[j];
    }
  }
  __syncthreads();
  const int rp = t >> 3, k0 = (t & 7) * 8;
  unsigned wds[8];
#pragma unroll
  for (int i = 0; i < 8; ++i) wds[i] = *(const unsigned*)&T[k0 + i][2 * rp];
  bf16x8 r0, r1; unzip8(wds, &r0, &r1);
  __bf16* d0 = dst0 + (size_t)(2 * rp) * dst_stride + k0;
  *(bf16x8*)d0 = r0;
  *(bf16x8*)(d0 + dst_stride) = r1;
}

// ---------------------------------------------------------------- attention
// 1024 blocks (1-D, XCD-chunked swizzle), 512 thr = 8 waves = qg{0,1} x
// kh{0..3}; wave = 32q x 32kv-quarter. KVBLK=128, 16 iters, SINGLE-buffered
// K/V: reads -> barrier A -> stage writes (overlap exp) -> PV (regs only)
// -> barrier B. LDS 36,864 B -> 4 blocks/CU = 32 waves/CU.
__global__ __launch_bounds__(512, 4) void attn(
    const float* __restrict__ Qf, const __bf16* __restrict__ Kb,
    const __bf16* __restrict__ Vtg, __bf16* __restrict__ Cc) {
  __shared__ __align__(16) unsigned char lds_raw[36864];
  __bf16 (*Ks)[72]  = (__bf16 (*)[72])lds_raw;             // [128][72]
  __bf16 (*Vs)[136] = (__bf16 (*)[136])(lds_raw + 18432);  // [64][136]

  const int tid = threadIdx.x;
  const int wave = tid >> 6, lane = tid & 63;
  const int ln = lane & 31, g = lane >> 5;
  const int qg = wave >> 2, kh = wave & 3;
  // XCD-chunked bijective swizzle: 1024 = 8 XCD x 128; each XCD gets 128
  // consecutive work-ids = 4 full (h,bz) pairs -> K/V L2-resident per XCD.
  const int f = blockIdx.x;
  const int swz = (f & 7) * 128 + (f >> 3);
  const int qb = swz & 31, h = (swz >> 5) & 15, bz = swz >> 9;

  const size_t hoff = (size_t)(bz * Hn + h) * Sn * Dn;
  const float*  Qp = Qf + hoff + (size_t)(qb * 64 + qg * 32) * Dn;
  const __bf16* Kp = Kb + hoff;      // [kv][d]
  const __bf16* Vp = Vtg + hoff;     // [d][kv]

  // Q A-fragments: fp32 load + scale + cvt (prologue only)
  bf16x8 qf[4];
#pragma unroll
  for (int ks = 0; ks < 4; ++ks) {
    const float* qp = Qp + (size_t)ln * Dn + ks * 16 + g * 8;
    f32x4v f0 = *(const f32x4v*)qp;
    f32x4v f1 = *(const f32x4v*)(qp + 4);
#pragma unroll
    for (int j = 0; j < 4; ++j) {
      qf[ks][j]     = (__bf16)(f0[j] * QSCALE);
      qf[ks][4 + j] = (__bf16)(f1[j] * QSCALE);
    }
  }

  // staging maps: K tile [128 kv][64 d], V tile [64 d][128 kv] (permuted)
  const int kr = tid >> 2, kc = (tid & 3) * 16;   // K: 2 b128/thread
  const int vr = tid >> 3, vc = (tid & 7) * 16;   // V: 2 b128/thread
  const __bf16* kbase = Kp + (size_t)kr * Dn + kc;
  const __bf16* vbase = Vp + (size_t)vr * Sn + vc;

  // stage tile 0 (write immediately), then prefetch tile 1 into regs
  bf16x8 k0r = *(const bf16x8*)kbase, k1r = *(const bf16x8*)(kbase + 8);
  bf16x8 v0r = *(const bf16x8*)vbase, v1r = *(const bf16x8*)(vbase + 8);
  {
    *(bf16x8*)&Ks[kr][kc]     = k0r;
    *(bf16x8*)&Ks[kr][kc + 8] = k1r;
    union { bf16x8 v; bf16x4 h[2]; } u0, u1; u0.v = v0r; u1.v = v1r;
    union { bf16x4 h[2]; bf16x8 v; } w0, w1;
    w0.h[0] = u0.h[0]; w0.h[1] = u1.h[0];
    w1.h[0] = u0.h[1]; w1.h[1] = u1.h[1];
    *(bf16x8*)&Vs[vr][vc]     = w0.v;
    *(bf16x8*)&Vs[vr][vc + 8] = w1.v;
  }
  k0r = *(const bf16x8*)(kbase + (size_t)128 * Dn);
  k1r = *(const bf16x8*)(kbase + (size_t)128 * Dn + 8);
  v0r = *(const bf16x8*)(vbase + 128);
  v1r = *(const bf16x8*)(vbase + 128 + 8);
  LGKM_BARRIER();

  f32x16 O0 = {}, O1 = {};                   // O^T: d rows, q cols
  float Lown = 0.0f;
  constexpr int NT = Sn / 128;               // 16

  for (int kt = 0; kt < NT; ++kt) {
    // ---- reads of current tile ----
    bf16x8 kf[4];
#pragma unroll
    for (int ks = 0; ks < 4; ++ks)
      kf[ks] = *(const bf16x8*)&Ks[kh * 32 + ln][ks * 16 + g * 8];

    f32x16 s = {};
#pragma unroll
    for (int ks = 0; ks < 4; ++ks)
      s = __builtin_amdgcn_mfma_f32_32x32x16_bf16(kf[ks], qf[ks], s, 0, 0, 0);

    // PV V-fragments for this wave's kv quarter (read before barrier A)
    const int cb = kh * 32 + g * 8;
    bf16x8 vf00 = *(const bf16x8*)&Vs[ln][cb];
    bf16x8 vf01 = *(const bf16x8*)&Vs[32 + ln][cb];
    bf16x8 vf10 = *(const bf16x8*)&Vs[ln][cb + 16];
    bf16x8 vf11 = *(const bf16x8*)&Vs[32 + ln][cb + 16];

    LGKM_BARRIER();   // A: all waves' reads of current tile drained

    // ---- stage next tile (overlaps exp/PV below) ----
    if (kt + 1 < NT) {
      *(bf16x8*)&Ks[kr][kc]     = k0r;
      *(bf16x8*)&Ks[kr][kc + 8] = k1r;
      union { bf16x8 v; bf16x4 h[2]; } u0, u1; u0.v = v0r; u1.v = v1r;
      union { bf16x4 h[2]; bf16x8 v; } w0, w1;
      w0.h[0] = u0.h[0]; w0.h[1] = u1.h[0];
      w1.h[0] = u0.h[1]; w1.h[1] = u1.h[1];
      *(bf16x8*)&Vs[vr][vc]     = w0.v;
      *(bf16x8*)&Vs[vr][vc + 8] = w1.v;
      if (kt + 2 < NT) {
        const __bf16* kp = kbase + (size_t)(kt + 2) * 128 * Dn;
        k0r = *(const bf16x8*)kp; k1r = *(const bf16x8*)(kp + 8);
        const __bf16* vp = vbase + (kt + 2) * 128;
        v0r = *(const bf16x8*)vp; v1r = *(const bf16x8*)(vp + 8);
      }
    }

    // ---- softmax-exp + pack (VALU; hides staging-write latency) ----
    float p[16];
#pragma unroll
    for (int r = 0; r < 16; ++r) p[r] = __builtin_amdgcn_exp2f(s[r]);
    f32x2v s2 = {0.0f, 0.0f};
#pragma unroll
    for (int tt = 0; tt < 8; ++tt) { f32x2v t2 = {p[2 * tt], p[2 * tt + 1]}; s2 += t2; }
    Lown += s2[0] + s2[1];
    unsigned w[8];
#pragma unroll
    for (int tt = 0; tt < 8; ++tt) w[tt] = pack2(p[2 * tt], p[2 * tt + 1]);

    // ---- PV (registers only; overlaps staging writes) ----
#pragma unroll
    for (int s4 = 0; s4 < 2; ++s4) {
      union { unsigned u[4]; bf16x8 v; } pu;
      pu.u[0] = w[s4 * 4 + 0];
      pu.u[1] = w[s4 * 4 + 1];
      pu.u[2] = w[s4 * 4 + 2];
      pu.u[3] = w[s4 * 4 + 3];
      O0 = __builtin_amdgcn_mfma_f32_32x32x16_bf16(s4 ? vf10 : vf00, pu.v, O0, 0, 0, 0);
      O1 = __builtin_amdgcn_mfma_f32_32x32x16_bf16(s4 ? vf11 : vf01, pu.v, O1, 0, 0, 0);
    }

    LGKM_BARRIER();   // B: staged writes visible before next iter's reads
  }

  // ---- kh 4-way O/L reduction (2-stage pair tree via LDS), norm, store ----
  float Lacc = Lown + __shfl_xor(Lown, 32);  // merge g halves (same q)
  float* Ex = (float*)lds_raw;               // 4 x 64 x 36 f32 = 36,864 B
  // stage 1: kh {1,3} -> kh {0,2}
  {
    const int slot = (((qg << 1) | (kh >> 1)) * 64 + lane) * 36;
    if (kh & 1) {
#pragma unroll
      for (int i = 0; i < 4; ++i) {
        f32x4v t = {O0[4 * i], O0[4 * i + 1], O0[4 * i + 2], O0[4 * i + 3]};
        *(f32x4v*)&Ex[slot + 4 * i] = t;
      }
#pragma unroll
      for (int i = 0; i < 4; ++i) {
        f32x4v t = {O1[4 * i], O1[4 * i + 1], O1[4 * i + 2], O1[4 * i + 3]};
        *(f32x4v*)&Ex[slot + 16 + 4 * i] = t;
      }
      Ex[slot + 32] = Lacc;
    }
    __syncthreads();
    if (!(kh & 1)) {
#pragma unroll
      for (int i = 0; i < 4; ++i) {
        f32x4v t = *(const f32x4v*)&Ex[slot + 4 * i];
#pragma unroll
        for (int c = 0; c < 4; ++c) O0[4 * i + c] += t[c];
      }
#pragma unroll
      for (int i = 0; i < 4; ++i) {
        f32x4v t = *(const f32x4v*)&Ex[slot + 16 + 4 * i];
#pragma unroll
        for (int c = 0; c < 4; ++c) O1[4 * i + c] += t[c];
      }
      Lacc += Ex[slot + 32];
    }
    __syncthreads();
  }
  // stage 2: kh==2 -> kh==0
  float inv = 0.0f;
  {
    const int slot2 = (qg * 64 + lane) * 36;
    if (kh == 2) {
#pragma unroll
      for (int i = 0; i < 4; ++i) {
        f32x4v t = {O0[4 * i], O0[4 * i + 1], O0[4 * i + 2], O0[4 * i + 3]};
        *(f32x4v*)&Ex[slot2 + 4 * i] = t;
      }
#pragma unroll
      for (int i = 0; i < 4; ++i) {
        f32x4v t = {O1[4 * i], O1[4 * i + 1], O1[4 * i + 2], O1[4 * i + 3]};
        *(f32x4v*)&Ex[slot2 + 16 + 4 * i] = t;
      }
      Ex[slot2 + 32] = Lacc;
    }
    __syncthreads();
    if (kh == 0) {
#pragma unroll
      for (int i = 0; i < 4; ++i) {
        f32x4v t = *(const f32x4v*)&Ex[slot2 + 4 * i];
#pragma unroll
        for (int c = 0; c < 4; ++c) O0[4 * i + c] += t[c];
      }
#pragma unroll
      for (int i = 0; i < 4; ++i) {
        f32x4v t = *(const f32x4v*)&Ex[slot2 + 16 + 4 * i];
#pragma unroll
        for (int c = 0; c < 4; ++c) O1[4 * i + c] += t[c];
      }
      inv = 1.0f / (Lacc + Ex[slot2 + 32]);
    }
    __syncthreads();   // all stage-2 reads done before T overwrites Ex
  }
  __bf16* T = (__bf16*)lds_raw;              // [64][72] bf16 = 9,216 B
  if (kh == 0) {
#pragma unroll
    for (int dh = 0; dh < 2; ++dh) {
#pragma unroll
      for (int a = 0; a < 4; ++a) {
        const f32x16 O = dh ? O1 : O0;
        bf16x4 t4;
#pragma unroll
        for (int c = 0; c < 4; ++c) t4[c] = (__bf16)(O[4 * a + c] * inv);
        *(bf16x4*)&T[(qg * 32 + ln) * 72 + dh * 32 + 8 * a + 4 * g] = t4;
      }
    }
  }
  __syncthreads();
  const int q0 = qb * 64;
  {
    const int rq = tid >> 3;                 // 0..63
    const int c8 = (tid & 7) * 8;
    bf16x8 o = *(const bf16x8*)&T[rq * 72 + c8];
    size_t base = (((size_t)bz * Sn + q0 + rq) * Hn + h) * Dn + c8;
    *(bf16x8*)&Cc[base] = o;
  }
}

// ---------------------------------------------------------------- projection
// out(4096,1024) = concat @ W + b. 128x64 tile, 512 threads = 8 waves
// (wave = M-quadrant mq x N-half nh), dbuf, one barrier/iter. 16 waves/CU.
__global__ __launch_bounds__(512, 2) void proj(
    const __bf16* __restrict__ A, const __bf16* __restrict__ Wt,
    const float* __restrict__ bias, float* __restrict__ out) {
  const int tid = threadIdx.x, wave = tid >> 6, lane = tid & 63;
  const int ln = lane & 31, g = lane >> 5;
  const int mq = wave >> 1, nh = wave & 1;
  const int bm = blockIdx.x, bn = blockIdx.y;
  __shared__ __bf16 As[2][128][72];
  __shared__ __bf16 Bs[2][64][72];
  const int ar = tid >> 2, ac = (tid & 3) * 16;   // A: 2 b128/thread
  const int rb = tid >> 3, cb = (tid & 7) * 8;    // B: 1 b128/thread
  f32x16 acc = {};
  const __bf16* Ap = A + (size_t)(bm * 128) * DM;
  const __bf16* Wp = Wt + (size_t)(bn * 64) * DM;

  bf16x8 a0, a1, b0;
  {
    const __bf16* ap = Ap + (size_t)ar * DM + ac;
    a0 = *(const bf16x8*)ap; a1 = *(const bf16x8*)(ap + 8);
    b0 = *(const bf16x8*)(Wp + (size_t)rb * DM + cb);
  }
  *(bf16x8*)&As[0][ar][ac]     = a0;
  *(bf16x8*)&As[0][ar][ac + 8] = a1;
  *(bf16x8*)&Bs[0][rb][cb]     = b0;
  {
    const __bf16* ap = Ap + (size_t)ar * DM + 64 + ac;
    a0 = *(const bf16x8*)ap; a1 = *(const bf16x8*)(ap + 8);
    b0 = *(const bf16x8*)(Wp + (size_t)rb * DM + 64 + cb);
  }
  LGKM_BARRIER();

  constexpr int KT = DM / 64;
  for (int kt = 0; kt < KT; ++kt) {
    const int buf = kt & 1;
    __builtin_amdgcn_s_setprio(1);
#pragma unroll
    for (int ks = 0; ks < 4; ++ks) {
      bf16x8 af = *(const bf16x8*)&As[buf][mq * 32 + ln][ks * 16 + g * 8];
      bf16x8 wf = *(const bf16x8*)&Bs[buf][nh * 32 + ln][ks * 16 + g * 8];
      acc = __builtin_amdgcn_mfma_f32_32x32x16_bf16(af, wf, acc, 0, 0, 0);
    }
    __builtin_amdgcn_s_setprio(0);
    if (kt + 1 < KT) {
      const int nb = buf ^ 1;
      *(bf16x8*)&As[nb][ar][ac]     = a0;
      *(bf16x8*)&As[nb][ar][ac + 8] = a1;
      *(bf16x8*)&Bs[nb][rb][cb]     = b0;
      if (kt + 2 < KT) {
        const __bf16* ap = Ap + (size_t)ar * DM + (kt + 2) * 64 + ac;
        a0 = *(const bf16x8*)ap; a1 = *(const bf16x8*)(ap + 8);
        b0 = *(const bf16x8*)(Wp + (size_t)rb * DM + (kt + 2) * 64 + cb);
      }
    }
    LGKM_BARRIER();
  }
  const float bv = bias[bn * 64 + nh * 32 + ln];
#pragma unroll
  for (int r = 0; r < 16; ++r) {
    int row = bm * 128 + mq * 32 + (r & 3) + 8 * (r >> 2) + 4 * g;
    out[(size_t)row * DM + bn * 64 + nh * 32 + ln] = acc[r] + bv;
  }
}

// ---------------------------------------------------------------- launch
extern "C" void kernel_launch(void* const* d_in, const int* in_sizes, int n_in,
                              void* d_out, int out_size, void* d_ws, size_t ws_size,
                              hipStream_t stream) {
  const float* Q = (const float*)d_in[0];
  const float* K = (const float*)d_in[1];
  const float* V = (const float*)d_in[2];
  const float* W = (const float*)d_in[3];
  const float* b = (const float*)d_in[4];
  float* out = (float*)d_out;

  __bf16* ws  = (__bf16*)d_ws;
  __bf16* Kb  = ws;
  __bf16* Vtg = Kb + QKV_ELEMS;               // (b,h,d,kv) bf16
  __bf16* Cc  = Vtg + QKV_ELEMS;              // concat (B,S,H,D) bf16
  __bf16* Wt  = Cc + QKV_ELEMS;               // (n,k) bf16

  convert_all<<<dim3(3328, 1, 1), 256, 0, stream>>>(K, V, W, Kb, Vtg, Wt);
  attn<<<dim3(1024, 1, 1), 512, 0, stream>>>(Q, Kb, Vtg, Cc);
  proj<<<dim3(Bn * Sn / 128, DM / 64, 1), 512, 0, stream>>>(Cc, Wt, b, out);
}

// Round 5
// 152.455 us; speedup vs baseline: 1.0898x; 1.0898x over previous
//
#include <hip/hip_runtime.h>
#include <hip/hip_bf16.h>

// B=2, H=16, S=2048, D=64, DMODEL=1024
// Round 15: r14 post-mortem -- XCD swizzle VERIFIED (FETCH 74->17MB) but
// sbuf 2-barrier lockstep regressed attn 52->66. Revert attn to r13's proven
// dbuf structure + keep swizzle. NEW: totals show convert+proj = ~105us
// every round (rooflines ~9+13us). proj provably re-reads A 16x / W 32x
// (~200MB). Fix proj block->tile map only: XCD-chunked, bn-fastest (per-XCD
// working set A 1MB + W 2MB fits 4MB L2). convert untouched (diagnostic:
// if proj drops below it, convert shows in next top-5).

typedef float  f32x16 __attribute__((ext_vector_type(16)));
typedef float  f32x4v __attribute__((ext_vector_type(4)));
typedef float  f32x2v __attribute__((ext_vector_type(2)));
typedef __bf16 bf16x8 __attribute__((ext_vector_type(8)));
typedef __bf16 bf16x4 __attribute__((ext_vector_type(4)));
typedef __bf16 bf16x2 __attribute__((ext_vector_type(2)));

static constexpr int Bn = 2, Hn = 16, Sn = 2048, Dn = 64, DM = 1024;
static constexpr size_t QKV_ELEMS = (size_t)Bn * Hn * Sn * Dn;   // 4,194,304

#define QSCALE 0.18033688011112042f   // 0.125 * log2(e)

// lgkm-only barrier: LDS writes drained, global prefetch stays in flight.
#define LGKM_BARRIER() do {                                  \
    asm volatile("s_waitcnt lgkmcnt(0)" ::: "memory");       \
    __builtin_amdgcn_s_barrier();                            \
  } while (0)

#if __has_builtin(__builtin_amdgcn_cvt_pk_bf16_f32)
static __device__ __forceinline__ unsigned pack2(float a, float b) {
  bf16x2 t = __builtin_amdgcn_cvt_pk_bf16_f32(a, b);
  union { bf16x2 v; unsigned u; } c; c.v = t; return c.u;
}
#else
static __device__ __forceinline__ unsigned pack2(float a, float b) {
  union { __bf16 h; unsigned short s; } ua, ub;
  ua.h = (__bf16)a; ub.h = (__bf16)b;
  return (unsigned)ua.s | ((unsigned)ub.s << 16);
}
#endif

static __device__ __forceinline__ void unzip8(const unsigned* wds, bf16x8* r0, bf16x8* r1) {
  union { unsigned u[4]; bf16x8 v; } a, b;
#pragma unroll
  for (int i = 0; i < 4; ++i) {
    unsigned lo = wds[2 * i], hi = wds[2 * i + 1];
    a.u[i] = (lo & 0xffffu) | (hi << 16);
    b.u[i] = (lo >> 16) | (hi & 0xffff0000u);
  }
  *r0 = a.v; *r1 = b.v;
}

// ------------------------------------------------- fused converts (1 kernel)
// [0,2048) K cvt; [2048,3072) V-T; [3072,3328) W-T. (Q handled inside attn.)
__global__ __launch_bounds__(256) void convert_all(
    const float* __restrict__ k,
    const float* __restrict__ v, const float* __restrict__ w,
    __bf16* __restrict__ ko,
    __bf16* __restrict__ vt, __bf16* __restrict__ wt) {
  __shared__ __bf16 T[64][74];
  const int bid = blockIdx.x, t = threadIdx.x;

  if (bid < 2048) {
    size_t i = ((size_t)bid * 256 + t) * 8;
    f32x4v a = *(const f32x4v*)(k + i);
    f32x4v b = *(const f32x4v*)(k + i + 4);
    bf16x8 o;
#pragma unroll
    for (int j = 0; j < 4; ++j) { o[j] = (__bf16)a[j]; o[4 + j] = (__bf16)b[j]; }
    *(bf16x8*)(ko + i) = o;
    return;
  }

  const float* s0;
  __bf16* dst0;
  size_t dst_stride;
  {
    const int r = t >> 2, c0 = (t & 3) * 16;
    if (bid < 3072) {
      const int idx = bid - 2048;
      const int kv0 = (idx & 31) * 64, bh = idx >> 5;
      s0 = v + ((size_t)bh * Sn + kv0 + r) * Dn + c0;
      dst0 = vt + (size_t)bh * Dn * Sn + kv0;
      dst_stride = Sn;
    } else {
      const int idx = bid - 3072;
      const int nt = (idx & 15) * 64, kt = (idx >> 4) * 64;
      s0 = w + (size_t)(kt + r) * DM + nt + c0;
      dst0 = wt + (size_t)nt * DM + kt;
      dst_stride = DM;
    }
    union { bf16x8 v8; unsigned u[4]; } o0, o1;
#pragma unroll
    for (int i = 0; i < 2; ++i) {
      f32x4v f = *(const f32x4v*)(s0 + i * 4);
#pragma unroll
      for (int j = 0; j < 4; ++j) o0.v8[i * 4 + j] = (__bf16)f[j];
    }
#pragma unroll
    for (int i = 0; i < 2; ++i) {
      f32x4v f = *(const f32x4v*)(s0 + 8 + i * 4);
#pragma unroll
      for (int j = 0; j < 4; ++j) o1.v8[i * 4 + j] = (__bf16)f[j];
    }
#pragma unroll
    for (int j = 0; j < 4; ++j) {
      *(unsigned*)&T[r][c0 + 2 * j]     = o0.u[j];
      *(unsigned*)&T[r][c0 + 8 + 2 * j] = o1.u[j];
    }
  }
  __syncthreads();
  const int rp = t >> 3, k0 = (t & 7) * 8;
  unsigned wds[8];
#pragma unroll
  for (int i = 0; i < 8; ++i) wds[i] = *(const unsigned*)&T[k0 + i][2 * rp];
  bf16x8 r0, r1; unzip8(wds, &r0, &r1);
  __bf16* d0 = dst0 + (size_t)(2 * rp) * dst_stride + k0;
  *(bf16x8*)d0 = r0;
  *(bf16x8*)(d0 + dst_stride) = r1;
}

// ---------------------------------------------------------------- attention
// r13 structure (proven 52us): 512 blocks, 8 waves = (qg x 32q, kh x
// 64kv-half), KVBLK=128, dbuf, 1 lgkm-barrier/iter. NEW: 1-D grid with
// XCD-chunked swizzle (512 = 8 XCD x 64; per XCD 64 blocks = 2 (h,bz)
// pairs -> K/V 2MB L2-resident, verified mechanism in r14).
__global__ __launch_bounds__(512, 4) void attn(
    const float* __restrict__ Qf, const __bf16* __restrict__ Kb,
    const __bf16* __restrict__ Vtg, __bf16* __restrict__ Cc) {
  const int tid = threadIdx.x;
  const int wave = tid >> 6, lane = tid & 63;
  const int ln = lane & 31, g = lane >> 5;
  const int qg = wave >> 1, kh = wave & 1;
  // XCD-chunked bijective swizzle: f&7 = XCD (verified r14), 64 chunks each.
  const int f = blockIdx.x;
  const int swz = (f & 7) * 64 + (f >> 3);
  const int qb = swz & 15, h = (swz >> 4) & 15, bz = swz >> 8;

  __shared__ __bf16 Ks[2][128][72];          // 36864 B
  __shared__ __bf16 Vs[2][64][136];          // 34816 B -> 71680 total, 2 blk/CU

  const size_t hoff = (size_t)(bz * Hn + h) * Sn * Dn;
  const float*  Qp = Qf + hoff + (size_t)(qb * 128 + qg * 32) * Dn;
  const __bf16* Kp = Kb + hoff;      // [kv][d]
  const __bf16* Vp = Vtg + hoff;     // [d][kv]

  // Q A-fragments: fp32 load + scale + cvt (prologue only)
  bf16x8 qf[4];
#pragma unroll
  for (int ks = 0; ks < 4; ++ks) {
    const float* qp = Qp + (size_t)ln * Dn + ks * 16 + g * 8;
    f32x4v f0 = *(const f32x4v*)qp;
    f32x4v f1 = *(const f32x4v*)(qp + 4);
#pragma unroll
    for (int j = 0; j < 4; ++j) {
      qf[ks][j]     = (__bf16)(f0[j] * QSCALE);
      qf[ks][4 + j] = (__bf16)(f1[j] * QSCALE);
    }
  }

  // staging maps: K tile [128 kv][64 d] (32 B/thread), V tile [64 d][128 kv]
  const int kr = tid >> 2, kc = (tid & 3) * 16;   // K: 2 b128/thread
  const int vr = tid >> 3, vc = (tid & 7) * 16;   // V: 2 b128/thread (permuted)
  const __bf16* kbase = Kp + (size_t)kr * Dn + kc;
  const __bf16* vbase = Vp + (size_t)vr * Sn + vc;

  // stage tile 0
  bf16x8 k0r = *(const bf16x8*)kbase, k1r = *(const bf16x8*)(kbase + 8);
  bf16x8 v0r = *(const bf16x8*)vbase, v1r = *(const bf16x8*)(vbase + 8);
  {
    *(bf16x8*)&Ks[0][kr][kc]     = k0r;
    *(bf16x8*)&Ks[0][kr][kc + 8] = k1r;
    union { bf16x8 v; bf16x4 h[2]; } u0, u1; u0.v = v0r; u1.v = v1r;
    union { bf16x4 h[2]; bf16x8 v; } w0, w1;
    w0.h[0] = u0.h[0]; w0.h[1] = u1.h[0];
    w1.h[0] = u0.h[1]; w1.h[1] = u1.h[1];
    *(bf16x8*)&Vs[0][vr][vc]     = w0.v;
    *(bf16x8*)&Vs[0][vr][vc + 8] = w1.v;
  }
  // prefetch tile 1
  k0r = *(const bf16x8*)(kbase + (size_t)128 * Dn);
  k1r = *(const bf16x8*)(kbase + (size_t)128 * Dn + 8);
  v0r = *(const bf16x8*)(vbase + 128);
  v1r = *(const bf16x8*)(vbase + 128 + 8);
  LGKM_BARRIER();

  f32x16 O0 = {}, O1 = {};                   // O^T halves: d in [0,32),[32,64)
  float Lown = 0.0f;
  constexpr int NT = Sn / 128;               // 16

  for (int kt = 0; kt < NT; ++kt) {
    const int buf = kt & 1;

    // QK^T + softmax-exp in two m-halves (kv 32-row blocks of this kh half)
    unsigned w[16];
#pragma unroll
    for (int m = 0; m < 2; ++m) {
      bf16x8 kf[4];
#pragma unroll
      for (int ks = 0; ks < 4; ++ks)
        kf[ks] = *(const bf16x8*)&Ks[buf][kh * 64 + m * 32 + ln][ks * 16 + g * 8];

      f32x16 s = {};
      __builtin_amdgcn_s_setprio(1);
#pragma unroll
      for (int ks = 0; ks < 4; ++ks)
        s = __builtin_amdgcn_mfma_f32_32x32x16_bf16(kf[ks], qf[ks], s, 0, 0, 0);
      __builtin_amdgcn_s_setprio(0);

      float p[16];
#pragma unroll
      for (int r = 0; r < 16; ++r) p[r] = __builtin_amdgcn_exp2f(s[r]);
      f32x2v s2 = {0.0f, 0.0f};
#pragma unroll
      for (int tt = 0; tt < 8; ++tt) { f32x2v t2 = {p[2 * tt], p[2 * tt + 1]}; s2 += t2; }
      Lown += s2[0] + s2[1];
#pragma unroll
      for (int tt = 0; tt < 8; ++tt) w[m * 8 + tt] = pack2(p[2 * tt], p[2 * tt + 1]);
    }

    if (kt + 1 < NT) {
      const int nb = buf ^ 1;
      *(bf16x8*)&Ks[nb][kr][kc]     = k0r;
      *(bf16x8*)&Ks[nb][kr][kc + 8] = k1r;
      union { bf16x8 v; bf16x4 h[2]; } u0, u1; u0.v = v0r; u1.v = v1r;
      union { bf16x4 h[2]; bf16x8 v; } w0, w1;
      w0.h[0] = u0.h[0]; w0.h[1] = u1.h[0];
      w1.h[0] = u0.h[1]; w1.h[1] = u1.h[1];
      *(bf16x8*)&Vs[nb][vr][vc]     = w0.v;
      *(bf16x8*)&Vs[nb][vr][vc + 8] = w1.v;
      if (kt + 2 < NT) {
        const __bf16* kp = kbase + (size_t)(kt + 2) * 128 * Dn;
        k0r = *(const bf16x8*)kp; k1r = *(const bf16x8*)(kp + 8);
        const __bf16* vp = vbase + (kt + 2) * 128;
        v0r = *(const bf16x8*)vp; v1r = *(const bf16x8*)(vp + 8);
      }
    }

    // PV over this wave's 64-kv half: 4 k-slices; permuted V^T supplies each
    // 8-kv group as ONE contiguous b128 at col kh*64 + s4*16 + g*8.
    __builtin_amdgcn_s_setprio(1);
#pragma unroll
    for (int s4 = 0; s4 < 4; ++s4) {
      const int cb = kh * 64 + s4 * 16 + g * 8;
      bf16x8 vf0 = *(const bf16x8*)&Vs[buf][ln][cb];
      bf16x8 vf1 = *(const bf16x8*)&Vs[buf][32 + ln][cb];
      union { unsigned u[4]; bf16x8 v; } pu;
      pu.u[0] = w[s4 * 4 + 0];
      pu.u[1] = w[s4 * 4 + 1];
      pu.u[2] = w[s4 * 4 + 2];
      pu.u[3] = w[s4 * 4 + 3];
      O0 = __builtin_amdgcn_mfma_f32_32x32x16_bf16(vf0, pu.v, O0, 0, 0, 0);
      O1 = __builtin_amdgcn_mfma_f32_32x32x16_bf16(vf1, pu.v, O1, 0, 0, 0);
    }
    __builtin_amdgcn_s_setprio(0);

    LGKM_BARRIER();
  }

  // ---- kh pair-reduction via LDS; normalize; transpose; coalesced store ----
  const float Lred = Lown + __shfl_xor(Lown, 32);
  float* Ex = (float*)Ks;                    // 256 slots x 36 f32 = 36864 B
  const int slot = (qg * 64 + lane) * 36;
  if (kh == 1) {
#pragma unroll
    for (int i = 0; i < 4; ++i) {
      f32x4v t = {O0[4 * i], O0[4 * i + 1], O0[4 * i + 2], O0[4 * i + 3]};
      *(f32x4v*)&Ex[slot + 4 * i] = t;
    }
#pragma unroll
    for (int i = 0; i < 4; ++i) {
      f32x4v t = {O1[4 * i], O1[4 * i + 1], O1[4 * i + 2], O1[4 * i + 3]};
      *(f32x4v*)&Ex[slot + 16 + 4 * i] = t;
    }
    Ex[slot + 32] = Lred;
  }
  __syncthreads();
  __bf16* T = (__bf16*)Vs;                   // [128][72] bf16 = 18432 B
  if (kh == 0) {
    float inv;
#pragma unroll
    for (int i = 0; i < 4; ++i) {
      f32x4v t = *(const f32x4v*)&Ex[slot + 4 * i];
#pragma unroll
      for (int c = 0; c < 4; ++c) O0[4 * i + c] += t[c];
    }
#pragma unroll
    for (int i = 0; i < 4; ++i) {
      f32x4v t = *(const f32x4v*)&Ex[slot + 16 + 4 * i];
#pragma unroll
      for (int c = 0; c < 4; ++c) O1[4 * i + c] += t[c];
    }
    inv = 1.0f / (Lred + Ex[slot + 32]);
#pragma unroll
    for (int dh = 0; dh < 2; ++dh) {
#pragma unroll
      for (int a = 0; a < 4; ++a) {
        const f32x16 O = dh ? O1 : O0;
        bf16x4 t4;
#pragma unroll
        for (int c = 0; c < 4; ++c) t4[c] = (__bf16)(O[4 * a + c] * inv);
        *(bf16x4*)&T[(qg * 32 + ln) * 72 + dh * 32 + 8 * a + 4 * g] = t4;
      }
    }
  }
  __syncthreads();
  const int q0 = qb * 128;
#pragma unroll
  for (int i = 0; i < 2; ++i) {
    const int rq = i * 64 + (tid >> 3);
    const int c8 = (tid & 7) * 8;
    bf16x8 o = *(const bf16x8*)&T[rq * 72 + c8];
    size_t base = (((size_t)bz * Sn + q0 + rq) * Hn + h) * Dn + c8;
    *(bf16x8*)&Cc[base] = o;
  }
}

// ---------------------------------------------------------------- projection
// out(4096,1024) = concat @ W + b. 128x64 tile, 512 threads = 8 waves,
// dbuf, one barrier/iter. r15: block->(bm,bn) map is now XCD-chunked,
// bn-fastest: per XCD working set = A panel (4 bm x 256KB = 1MB) + full W
// (2MB) = 3MB <= 4MB L2 -> HBM ~200MB -> ~41MB.
__global__ __launch_bounds__(512, 2) void proj(
    const __bf16* __restrict__ A, const __bf16* __restrict__ Wt,
    const float* __restrict__ bias, float* __restrict__ out) {
  const int tid = threadIdx.x, wave = tid >> 6, lane = tid & 63;
  const int ln = lane & 31, g = lane >> 5;
  const int mq = wave >> 1, nh = wave & 1;
  // XCD-chunked map: 512 blocks = 8 XCD x 64; within XCD: bn fastest (16),
  // then 4 bm rows -> A panel + W stay L2-resident per XCD.
  const int f = blockIdx.x;
  const int idx = f >> 3;
  const int bn = idx & 15;
  const int bm = (f & 7) * 4 + (idx >> 4);
  __shared__ __bf16 As[2][128][72];
  __shared__ __bf16 Bs[2][64][72];
  const int ar = tid >> 2, ac = (tid & 3) * 16;   // A: 2 b128/thread
  const int rb = tid >> 3, cb = (tid & 7) * 8;    // B: 1 b128/thread
  f32x16 acc = {};
  const __bf16* Ap = A + (size_t)(bm * 128) * DM;
  const __bf16* Wp = Wt + (size_t)(bn * 64) * DM;

  bf16x8 a0, a1, b0;
  {
    const __bf16* ap = Ap + (size_t)ar * DM + ac;
    a0 = *(const bf16x8*)ap; a1 = *(const bf16x8*)(ap + 8);
    b0 = *(const bf16x8*)(Wp + (size_t)rb * DM + cb);
  }
  *(bf16x8*)&As[0][ar][ac]     = a0;
  *(bf16x8*)&As[0][ar][ac + 8] = a1;
  *(bf16x8*)&Bs[0][rb][cb]     = b0;
  {
    const __bf16* ap = Ap + (size_t)ar * DM + 64 + ac;
    a0 = *(const bf16x8*)ap; a1 = *(const bf16x8*)(ap + 8);
    b0 = *(const bf16x8*)(Wp + (size_t)rb * DM + 64 + cb);
  }
  LGKM_BARRIER();

  constexpr int KT = DM / 64;
  for (int kt = 0; kt < KT; ++kt) {
    const int buf = kt & 1;
    __builtin_amdgcn_s_setprio(1);
#pragma unroll
    for (int ks = 0; ks < 4; ++ks) {
      bf16x8 af = *(const bf16x8*)&As[buf][mq * 32 + ln][ks * 16 + g * 8];
      bf16x8 wf = *(const bf16x8*)&Bs[buf][nh * 32 + ln][ks * 16 + g * 8];
      acc = __builtin_amdgcn_mfma_f32_32x32x16_bf16(af, wf, acc, 0, 0, 0);
    }
    __builtin_amdgcn_s_setprio(0);
    if (kt + 1 < KT) {
      const int nb = buf ^ 1;
      *(bf16x8*)&As[nb][ar][ac]     = a0;
      *(bf16x8*)&As[nb][ar][ac + 8] = a1;
      *(bf16x8*)&Bs[nb][rb][cb]     = b0;
      if (kt + 2 < KT) {
        const __bf16* ap = Ap + (size_t)ar * DM + (kt + 2) * 64 + ac;
        a0 = *(const bf16x8*)ap; a1 = *(const bf16x8*)(ap + 8);
        b0 = *(const bf16x8*)(Wp + (size_t)rb * DM + (kt + 2) * 64 + cb);
      }
    }
    LGKM_BARRIER();
  }
  const float bv = bias[bn * 64 + nh * 32 + ln];
#pragma unroll
  for (int r = 0; r < 16; ++r) {
    int row = bm * 128 + mq * 32 + (r & 3) + 8 * (r >> 2) + 4 * g;
    out[(size_t)row * DM + bn * 64 + nh * 32 + ln] = acc[r] + bv;
  }
}

// ---------------------------------------------------------------- launch
extern "C" void kernel_launch(void* const* d_in, const int* in_sizes, int n_in,
                              void* d_out, int out_size, void* d_ws, size_t ws_size,
                              hipStream_t stream) {
  const float* Q = (const float*)d_in[0];
  const float* K = (const float*)d_in[1];
  const float* V = (const float*)d_in[2];
  const float* W = (const float*)d_in[3];
  const float* b = (const float*)d_in[4];
  float* out = (float*)d_out;

  __bf16* ws  = (__bf16*)d_ws;
  __bf16* Kb  = ws;
  __bf16* Vtg = Kb + QKV_ELEMS;               // (b,h,d,kv) bf16
  __bf16* Cc  = Vtg + QKV_ELEMS;              // concat (B,S,H,D) bf16
  __bf16* Wt  = Cc + QKV_ELEMS;               // (n,k) bf16

  convert_all<<<dim3(3328, 1, 1), 256, 0, stream>>>(K, V, W, Kb, Vtg, Wt);
  attn<<<dim3(512, 1, 1), 512, 0, stream>>>(Q, Kb, Vtg, Cc);
  proj<<<dim3(512, 1, 1), 512, 0, stream>>>(Cc, Wt, b, out);
}